// Round 9
// baseline (214.896 us; speedup 1.0000x reference)
//
#include <hip/hip_runtime.h>
#include <hip/hip_bf16.h>

typedef __attribute__((ext_vector_type(8))) short sh8;
typedef __attribute__((ext_vector_type(4))) float f32x4;

#define MFMA16(a, b, c) __builtin_amdgcn_mfma_f32_16x16x32_bf16((a), (b), (c), 0, 0, 0)

__device__ __forceinline__ unsigned short f2bf(float f) {
    return (unsigned short)((__float_as_uint(f) + 0x8000u) >> 16);
}
__device__ __forceinline__ unsigned int pack2bf(float lo, float hi) {
    unsigned int ul = __float_as_uint(lo) + 0x8000u;
    unsigned int uh = __float_as_uint(hi) + 0x8000u;
    return __builtin_amdgcn_perm(uh, ul, 0x07060302u);
}
__device__ __forceinline__ float redmax_hi(float x) {
    x = fmaxf(x, __shfl_xor(x, 16, 64));
    return fmaxf(x, __shfl_xor(x, 32, 64));
}
__device__ __forceinline__ float redsum_hi(float x) {
    x += __shfl_xor(x, 16, 64);
    return x + __shfl_xor(x, 32, 64);
}
// async global->LDS, 16B per lane; LDS dest = wave-uniform base + lane*16
__device__ __forceinline__ void gload_lds16(const void* g, void* l) {
    __builtin_amdgcn_global_load_lds(
        (const __attribute__((address_space(1))) unsigned int*)g,
        (__attribute__((address_space(3))) unsigned int*)l, 16, 0, 0);
}

// ---------------------------------------------------------------------------
// f32 -> bf16 converters (memory-bound, run once instead of per GEMM tile)
// ---------------------------------------------------------------------------
__global__ __launch_bounds__(256) void cvt_x_k(
    const float* __restrict__ src, unsigned short* __restrict__ dst, int n4)
{
    int i = blockIdx.x * 256 + threadIdx.x;
    int stride = gridDim.x * 256;
    for (; i < n4; i += stride) {
        float4 v = ((const float4*)src)[i];
        uint2 h = { pack2bf(v.x, v.y), pack2bf(v.z, v.w) };
        ((uint2*)dst)[i] = h;
    }
}
// Wq,Wk,Wv,Wo (each 1024x1024 f32) -> wbf[4096][1024] bf16
__global__ __launch_bounds__(256) void cvt_w_k(
    const float* __restrict__ Wq, const float* __restrict__ Wk,
    const float* __restrict__ Wv, const float* __restrict__ Wo,
    unsigned short* __restrict__ wbf)
{
    int i = blockIdx.x * 256 + threadIdx.x;   // over 4*262144 float4s
    int seg = i >> 18;
    int off = i & 0x3FFFF;
    const float* s = (seg < 2) ? ((seg == 0) ? Wq : Wk) : ((seg == 2) ? Wv : Wo);
    float4 v = ((const float4*)s)[off];
    uint2 h = { pack2bf(v.x, v.y), pack2bf(v.z, v.w) };
    ((uint2*)wbf)[i] = h;
}

// ---------------------------------------------------------------------------
// Mask compaction (unchanged): list of kv indices with mask!=0.
// ---------------------------------------------------------------------------
__global__ __launch_bounds__(64) void compact_k(
    const int* __restrict__ mask, int* __restrict__ idx, int* __restrict__ cnt)
{
    const int b = blockIdx.x, l = threadIdx.x;
    const int* mb = mask + b * 2048;
    int base = 0;
    for (int i = 0; i < 32; ++i) {
        int m = mb[i * 64 + l];
        unsigned long long bal = __ballot(m != 0);
        int pre = __popcll(bal & ((1ull << l) - 1ull));
        if (m) idx[b * 2048 + base + pre] = i * 64 + l;
        base += (int)__popcll(bal);
    }
    if (base == 0) {
        for (int i = l; i < 2048; i += 64) idx[b * 2048 + i] = i;
        base = 2048;
    }
    if (l == 0) cnt[b] = base;
}

// ---------------------------------------------------------------------------
// QKV projection, m97-style (unchanged from R8).
// ---------------------------------------------------------------------------
__global__ __launch_bounds__(256) void gemm_qkv_k(
    const unsigned short* __restrict__ xbf,   // [M][1024]
    const unsigned short* __restrict__ wbf,   // [3072+][1024] rows = out cols
    unsigned short* __restrict__ qkv)
{
    __shared__ unsigned short As[128][32];
    __shared__ unsigned short Bs[128][32];
    const int tid = threadIdx.x;
    const int l = tid & 63, w = tid >> 6;
    const int wr = w >> 1, wc = w & 1;
    const long row0 = (long)blockIdx.y * 128;
    const int col0 = blockIdx.x * 128;

    f32x4 acc[4][4] = {};
    const int fr = l & 15, hi = l >> 4;

    const int sr = tid >> 2;
    const int sc = (tid & 3) * 8;
    const unsigned short* ga = &xbf[(row0 + sr) * 1024 + sc];
    const unsigned short* gb = &wbf[(long)(col0 + sr) * 1024 + sc];
    unsigned short* la = &As[w * 16][0];
    unsigned short* lb = &Bs[w * 16][0];

    for (int k0 = 0; k0 < 1024; k0 += 32) {
        __syncthreads();
        gload_lds16(ga + k0, la);
        gload_lds16(ga + 64 * 1024 + k0, la + 64 * 32);
        gload_lds16(gb + k0, lb);
        gload_lds16(gb + 64 * 1024 + k0, lb + 64 * 32);
        __syncthreads();

        sh8 af[4], bf[4];
#pragma unroll
        for (int i = 0; i < 4; ++i) {
            af[i] = *(const sh8*)&As[wr * 64 + i * 16 + fr][hi * 8];
            bf[i] = *(const sh8*)&Bs[wc * 64 + i * 16 + fr][hi * 8];
        }
#pragma unroll
        for (int i = 0; i < 4; ++i)
#pragma unroll
            for (int j = 0; j < 4; ++j)
                acc[i][j] = MFMA16(af[i], bf[j], acc[i][j]);
    }

    const float scale = (col0 < 1024) ? 0.1803368801f : 1.0f;
    const int rg = hi * 4, cg = l & 15;
#pragma unroll
    for (int i = 0; i < 4; ++i)
#pragma unroll
        for (int j = 0; j < 4; ++j) {
            long gr = row0 + wr * 64 + i * 16 + rg;
            int gc = col0 + wc * 64 + j * 16 + cg;
#pragma unroll
            for (int r = 0; r < 4; ++r)
                qkv[(gr + r) * 3072 + gc] = f2bf(acc[i][j][r] * scale);
        }
}

// ---------------------------------------------------------------------------
// Flash attention over COMPACTED kv list. R9: 1 q-group/wave (64 q/block,
// 2048 blocks) — halves per-wave VGPR+AGPR to climb the 128-reg occupancy
// cliff (R8: 140 combined -> 19.5% occupancy, latency-bound at 107us).
// Staging/swizzle/softmax/PV math identical to R8.
// ---------------------------------------------------------------------------
__global__ __launch_bounds__(256) void attn_k(
    const unsigned short* __restrict__ qkv, const int* __restrict__ idx,
    const int* __restrict__ cnt, unsigned short* __restrict__ ao, int b0)
{
    __shared__ unsigned short Kl[64][64];
    __shared__ unsigned short Vt[64][64];
    __shared__ float biasf[64];
    __shared__ unsigned short Pl[4][16][72];

    const int tid = threadIdx.x;
    const int l = tid & 63, w = tid >> 6;
    const int fr = l & 15, hi = l >> 4;

    // T1: bijective XCD swizzle
    int nwg = gridDim.x;
    int wgid = ((nwg & 7) == 0) ? ((blockIdx.x & 7) * (nwg >> 3) + (blockIdx.x >> 3))
                                : blockIdx.x;
    const int qb = wgid & 31;
    const int h  = (wgid >> 5) & 15;
    const int b  = wgid >> 9;
    const int q0 = qb * 64;
    const long base = (long)b * 2048;

    const int* idxb = idx + (size_t)(b0 + b) * 2048;
    const int nc = cnt[b0 + b];
    const int nt = (nc + 63) >> 6;

    // Q fragments: 1 q-group x 2 k-chunks, q = lane&15 (B-operand layout)
    sh8 qf0, qf1;
    {
        const unsigned short* qp = &qkv[(base + q0 + w * 16 + fr) * 3072 + h * 64 + hi * 8];
        qf0 = *(const sh8*)qp;
        qf1 = *(const sh8*)(qp + 32);
    }

    f32x4 acc[4] = {};
    float mrow = -1e30f;
    float lrow = 0.f;

    const int rK = tid >> 3, cc = tid & 7;
    const int kv2 = tid >> 3, dc = tid & 7;

    uint4 k0r, k1r, v0r, v1r;
    {
        int ik0 = idxb[min(rK, nc - 1)];
        int ik1 = idxb[min(rK + 32, nc - 1)];
        int iv0 = idxb[min(2 * kv2, nc - 1)];
        int iv1 = idxb[min(2 * kv2 + 1, nc - 1)];
        k0r = *(const uint4*)&qkv[(base + ik0) * 3072 + 1024 + h * 64 + cc * 8];
        k1r = *(const uint4*)&qkv[(base + ik1) * 3072 + 1024 + h * 64 + cc * 8];
        v0r = *(const uint4*)&qkv[(base + iv0) * 3072 + 2048 + h * 64 + dc * 8];
        v1r = *(const uint4*)&qkv[(base + iv1) * 3072 + 2048 + h * 64 + dc * 8];
    }

    for (int t = 0; t < nt; ++t) {
        __syncthreads();
        *(uint4*)&Kl[rK][(cc ^ (rK & 7)) * 8] = k0r;
        {
            int r2 = rK + 32;
            *(uint4*)&Kl[r2][(cc ^ (r2 & 7)) * 8] = k1r;
        }
        {
            unsigned int w0[4] = { v0r.x, v0r.y, v0r.z, v0r.w };
            unsigned int w1[4] = { v1r.x, v1r.y, v1r.z, v1r.w };
            int cc2 = kv2 >> 2, pos = (2 * kv2) & 7;
#pragma unroll
            for (int jj = 0; jj < 4; ++jj) {
                int de = dc * 8 + 2 * jj;
                unsigned int pe = (w0[jj] & 0xffffu) | (w1[jj] << 16);
                unsigned int po = (w0[jj] >> 16) | (w1[jj] & 0xffff0000u);
                int fde = (2 * jj) ^ dc;
                int fdo = (2 * jj + 1) ^ dc;
                *(unsigned int*)&Vt[de][((cc2 ^ fde) * 8) + pos] = pe;
                *(unsigned int*)&Vt[de + 1][((cc2 ^ fdo) * 8) + pos] = po;
            }
        }
        if (tid < 64) biasf[tid] = (t * 64 + tid < nc) ? 0.0f : -1e9f;
        __syncthreads();

        // T14: issue next tile's gather loads; land under this compute
        if (t + 1 < nt) {
            int s0 = (t + 1) * 64;
            int ik0 = idxb[min(s0 + rK, nc - 1)];
            int ik1 = idxb[min(s0 + rK + 32, nc - 1)];
            int iv0 = idxb[min(s0 + 2 * kv2, nc - 1)];
            int iv1 = idxb[min(s0 + 2 * kv2 + 1, nc - 1)];
            k0r = *(const uint4*)&qkv[(base + ik0) * 3072 + 1024 + h * 64 + cc * 8];
            k1r = *(const uint4*)&qkv[(base + ik1) * 3072 + 1024 + h * 64 + cc * 8];
            v0r = *(const uint4*)&qkv[(base + iv0) * 3072 + 2048 + h * 64 + dc * 8];
            v1r = *(const uint4*)&qkv[(base + iv1) * 3072 + 2048 + h * 64 + dc * 8];
        }

        // K fragments
        sh8 kf[4][2];
#pragma unroll
        for (int tt = 0; tt < 4; ++tt) {
            const unsigned short* kp = &Kl[tt * 16 + fr][0];
#pragma unroll
            for (int c = 0; c < 2; ++c)
                kf[tt][c] = *(const sh8*)&kp[((4 * c + hi) ^ (fr & 7)) * 8];
        }

        // S^T = K Q
        f32x4 s[4] = {};
        __builtin_amdgcn_s_setprio(1);
#pragma unroll
        for (int tt = 0; tt < 4; ++tt) {
            s[tt] = MFMA16(kf[tt][0], qf0, s[tt]);
            s[tt] = MFMA16(kf[tt][1], qf1, s[tt]);
        }
        __builtin_amdgcn_s_setprio(0);
#pragma unroll
        for (int tt = 0; tt < 4; ++tt)
            s[tt] += *(const f32x4*)&biasf[tt * 16 + 4 * hi];

        float pm = s[0][0];
#pragma unroll
        for (int tt = 0; tt < 4; ++tt)
#pragma unroll
            for (int r = 0; r < 4; ++r) pm = fmaxf(pm, s[tt][r]);
        pm = redmax_hi(pm);

        if (!__all(pm <= mrow)) {           // defer-max: wave-uniform skip
            float mn = fmaxf(mrow, pm);
            float scl = __builtin_amdgcn_exp2f(mrow - mn);
            lrow *= scl;
#pragma unroll
            for (int df = 0; df < 4; ++df) acc[df] *= scl;
            mrow = mn;
        }

        float ps = 0.f;
#pragma unroll
        for (int tt = 0; tt < 4; ++tt)
#pragma unroll
            for (int r = 0; r < 4; ++r) {
                float p = __builtin_amdgcn_exp2f(s[tt][r] - mrow);
                s[tt][r] = p;
                ps += p;
            }
        lrow += redsum_hi(ps);

        // P -> per-wave LDS (4x b64), rows q=fr, cols kv
#pragma unroll
        for (int tt = 0; tt < 4; ++tt) {
            uint2 pw = { pack2bf(s[tt][0], s[tt][1]), pack2bf(s[tt][2], s[tt][3]) };
            *(uint2*)&Pl[w][fr][tt * 16 + hi * 4] = pw;
        }

        // O^T += V^T * P
#pragma unroll
        for (int c = 0; c < 2; ++c) {
            sh8 pa = *(const sh8*)&Pl[w][fr][c * 32 + hi * 8];
            __builtin_amdgcn_s_setprio(1);
#pragma unroll
            for (int df = 0; df < 4; ++df) {
                int d = df * 16 + fr;
                int fd = (d & 7) ^ (d >> 3);
                sh8 vfr = *(const sh8*)&Vt[d][((4 * c + hi) ^ fd) * 8];
                acc[df] = MFMA16(vfr, pa, acc[df]);
            }
            __builtin_amdgcn_s_setprio(0);
        }
    }

    // epilogue
    {
        float inv = 1.0f / lrow;
        long qr = base + q0 + w * 16 + fr;
        unsigned short* op = &ao[qr * 1024 + h * 64];
#pragma unroll
        for (int df = 0; df < 4; ++df) {
            f32x4 o = acc[df];
            uint2 ow = { pack2bf(o[0] * inv, o[1] * inv), pack2bf(o[2] * inv, o[3] * inv) };
            *(uint2*)&op[df * 16 + hi * 4] = ow;
        }
    }
}

// ---------------------------------------------------------------------------
// Output projection, m97-style staging (unchanged from R8).
// ---------------------------------------------------------------------------
__global__ __launch_bounds__(256) void gemm_out_k(
    const unsigned short* __restrict__ ao, const unsigned short* __restrict__ wob,
    const float* __restrict__ bo, float* __restrict__ out)
{
    __shared__ unsigned short As[128][32];
    __shared__ unsigned short Bs[128][32];
    const int tid = threadIdx.x;
    const int l = tid & 63, w = tid >> 6;
    const int wr = w >> 1, wc = w & 1;
    const long row0 = (long)blockIdx.y * 128;
    const int col0 = blockIdx.x * 128;

    f32x4 acc[4][4] = {};
    const int fr = l & 15, hi = l >> 4;

    const int sr = tid >> 2;
    const int sc = (tid & 3) * 8;
    const unsigned short* ga = &ao[(row0 + sr) * 1024 + sc];
    const unsigned short* gb = &wob[(long)(col0 + sr) * 1024 + sc];
    unsigned short* la = &As[w * 16][0];
    unsigned short* lb = &Bs[w * 16][0];

    for (int k0 = 0; k0 < 1024; k0 += 32) {
        __syncthreads();
        gload_lds16(ga + k0, la);
        gload_lds16(ga + 64 * 1024 + k0, la + 64 * 32);
        gload_lds16(gb + k0, lb);
        gload_lds16(gb + 64 * 1024 + k0, lb + 64 * 32);
        __syncthreads();

        sh8 af[4], bf[4];
#pragma unroll
        for (int i = 0; i < 4; ++i) {
            af[i] = *(const sh8*)&As[wr * 64 + i * 16 + fr][hi * 8];
            bf[i] = *(const sh8*)&Bs[wc * 64 + i * 16 + fr][hi * 8];
        }
#pragma unroll
        for (int i = 0; i < 4; ++i)
#pragma unroll
            for (int j = 0; j < 4; ++j)
                acc[i][j] = MFMA16(af[i], bf[j], acc[i][j]);
    }

    const int rg = hi * 4, cg = l & 15;
#pragma unroll
    for (int i = 0; i < 4; ++i)
#pragma unroll
        for (int j = 0; j < 4; ++j) {
            long gr = row0 + wr * 64 + i * 16 + rg;
            int gc = col0 + wc * 64 + j * 16 + cg;
            float bb = bo[gc];
#pragma unroll
            for (int r = 0; r < 4; ++r)
                out[(gr + r) * 1024 + gc] = acc[i][j][r] + bb;
        }
}

extern "C" void kernel_launch(void* const* d_in, const int* in_sizes, int n_in,
                              void* d_out, int out_size, void* d_ws, size_t ws_size,
                              hipStream_t stream) {
    const float* x    = (const float*)d_in[0];
    const int*   mask = (const int*)d_in[1];
    const float* Wq   = (const float*)d_in[2];
    const float* Wk   = (const float*)d_in[3];
    const float* Wv   = (const float*)d_in[4];
    const float* Wo   = (const float*)d_in[5];
    const float* bo   = (const float*)d_in[6];
    float* out = (float*)d_out;

    const size_t wbf_bytes = (size_t)4096 * 1024 * 2;              // 8 MiB
    const size_t idx_bytes = (size_t)4 * 2048 * 4 + 64;
    const size_t xbf_per_b = (size_t)2048 * 1024 * 2;              // 4 MiB
    const size_t qkv_per_b = (size_t)2048 * 3072 * 2;              // 12 MiB
    const size_t ao_per_b  = (size_t)2048 * 1024 * 2;              // 4 MiB
    const size_t per_b = xbf_per_b + qkv_per_b + ao_per_b;         // 20 MiB

    size_t fixed = wbf_bytes + idx_bytes;
    size_t avail = (ws_size > fixed) ? (ws_size - fixed) : 0;
    int bchunk = (avail >= per_b) ? (int)(avail / per_b) : 1;
    if (bchunk > 4) bchunk = 4;

    char* p = (char*)d_ws;
    unsigned short* wbf = (unsigned short*)p;            p += wbf_bytes;
    int* idxp = (int*)p;                                 p += (size_t)4 * 2048 * 4;
    int* cntp = (int*)p;                                 p += 64;
    unsigned short* xbf = (unsigned short*)p;            p += (size_t)bchunk * xbf_per_b;
    unsigned short* qkv = (unsigned short*)p;            p += (size_t)bchunk * qkv_per_b;
    unsigned short* ao  = (unsigned short*)p;

    cvt_w_k<<<4096, 256, 0, stream>>>(Wq, Wk, Wv, Wo, wbf);
    compact_k<<<4, 64, 0, stream>>>(mask, idxp, cntp);

    for (int b0 = 0; b0 < 4; b0 += bchunk) {
        int bc = (4 - b0 < bchunk) ? (4 - b0) : bchunk;
        cvt_x_k<<<2048, 256, 0, stream>>>(
            x + (size_t)b0 * 2048 * 1024, xbf, bc * 524288);
        gemm_qkv_k<<<dim3(24, bc * 16), 256, 0, stream>>>(xbf, wbf, qkv);
        attn_k<<<dim3(512 * bc), 256, 0, stream>>>(qkv, idxp, cntp, ao, b0);
        gemm_out_k<<<dim3(8, bc * 16), 256, 0, stream>>>(
            ao, wbf + (size_t)3072 * 1024, bo, out + (size_t)b0 * 2048 * 1024);
    }
}

// Round 10
// 209.962 us; speedup vs baseline: 1.0235x; 1.0235x over previous
//
#include <hip/hip_runtime.h>
#include <hip/hip_bf16.h>

typedef __attribute__((ext_vector_type(8))) short sh8;
typedef __attribute__((ext_vector_type(4))) float f32x4;

#define MFMA16(a, b, c) __builtin_amdgcn_mfma_f32_16x16x32_bf16((a), (b), (c), 0, 0, 0)

__device__ __forceinline__ unsigned short f2bf(float f) {
    return (unsigned short)((__float_as_uint(f) + 0x8000u) >> 16);
}
__device__ __forceinline__ unsigned int pack2bf(float lo, float hi) {
    unsigned int ul = __float_as_uint(lo) + 0x8000u;
    unsigned int uh = __float_as_uint(hi) + 0x8000u;
    return __builtin_amdgcn_perm(uh, ul, 0x07060302u);
}
__device__ __forceinline__ float redmax_hi(float x) {
    x = fmaxf(x, __shfl_xor(x, 16, 64));
    return fmaxf(x, __shfl_xor(x, 32, 64));
}
__device__ __forceinline__ float redsum_hi(float x) {
    x += __shfl_xor(x, 16, 64);
    return x + __shfl_xor(x, 32, 64);
}
// async global->LDS, 16B per lane; LDS dest = wave-uniform base + lane*16
__device__ __forceinline__ void gload_lds16(const void* g, void* l) {
    __builtin_amdgcn_global_load_lds(
        (const __attribute__((address_space(1))) unsigned int*)g,
        (__attribute__((address_space(3))) unsigned int*)l, 16, 0, 0);
}

// ---------------------------------------------------------------------------
// f32 -> bf16 converters (run once)
// ---------------------------------------------------------------------------
__global__ __launch_bounds__(256) void cvt_x_k(
    const float* __restrict__ src, unsigned short* __restrict__ dst, int n4)
{
    int i = blockIdx.x * 256 + threadIdx.x;
    int stride = gridDim.x * 256;
    for (; i < n4; i += stride) {
        float4 v = ((const float4*)src)[i];
        uint2 h = { pack2bf(v.x, v.y), pack2bf(v.z, v.w) };
        ((uint2*)dst)[i] = h;
    }
}
__global__ __launch_bounds__(256) void cvt_w_k(
    const float* __restrict__ Wq, const float* __restrict__ Wk,
    const float* __restrict__ Wv, const float* __restrict__ Wo,
    unsigned short* __restrict__ wbf)
{
    int i = blockIdx.x * 256 + threadIdx.x;   // over 4*262144 float4s
    int seg = i >> 18;
    int off = i & 0x3FFFF;
    const float* s = (seg < 2) ? ((seg == 0) ? Wq : Wk) : ((seg == 2) ? Wv : Wo);
    float4 v = ((const float4*)s)[off];
    uint2 h = { pack2bf(v.x, v.y), pack2bf(v.z, v.w) };
    ((uint2*)wbf)[i] = h;
}

// ---------------------------------------------------------------------------
// Mask compaction (unchanged): list of kv indices with mask!=0.
// ---------------------------------------------------------------------------
__global__ __launch_bounds__(64) void compact_k(
    const int* __restrict__ mask, int* __restrict__ idx, int* __restrict__ cnt)
{
    const int b = blockIdx.x, l = threadIdx.x;
    const int* mb = mask + b * 2048;
    int base = 0;
    for (int i = 0; i < 32; ++i) {
        int m = mb[i * 64 + l];
        unsigned long long bal = __ballot(m != 0);
        int pre = __popcll(bal & ((1ull << l) - 1ull));
        if (m) idx[b * 2048 + base + pre] = i * 64 + l;
        base += (int)__popcll(bal);
    }
    if (base == 0) {
        for (int i = l; i < 2048; i += 64) idx[b * 2048 + i] = i;
        base = 2048;
    }
    if (l == 0) cnt[b] = base;
}

// ---------------------------------------------------------------------------
// R10: gather compacted K|V rows into dense Kc[b][i][2048]
// (cols 0..1023 = K, 1024..2047 = V for all 16 heads). Done ONCE per batch
// instead of re-gathered by every one of the 512 attn blocks.
// ---------------------------------------------------------------------------
__global__ __launch_bounds__(256) void kvgather_k(
    const unsigned short* __restrict__ qkv, const int* __restrict__ idx,
    const int* __restrict__ cnt, unsigned short* __restrict__ Kc, int b0)
{
    const int b = blockIdx.z;          // chunk-local batch
    const int t = blockIdx.y;          // kv tile 0..31
    const int z = blockIdx.x;          // row octet 0..7
    const int nc = cnt[b0 + b];
    if (t * 64 >= ((nc + 63) & ~63)) return;   // beyond padded count
    const int* idxb = idx + (size_t)(b0 + b) * 2048;
    const int tid = threadIdx.x;
    unsigned short* dst_b = Kc + (size_t)b * 2048 * 2048;
#pragma unroll
    for (int p = 0; p < 8; ++p) {
        int row = t * 64 + z * 8 + p;
        int src = idxb[min(row, nc - 1)];
        uint4 v = *(const uint4*)&qkv[((size_t)b * 2048 + src) * 3072 + 1024 + tid * 8];
        *(uint4*)&dst_b[(size_t)row * 2048 + tid * 8] = v;
    }
}

// ---------------------------------------------------------------------------
// QKV projection, m97-style (unchanged from R8/R9).
// ---------------------------------------------------------------------------
__global__ __launch_bounds__(256) void gemm_qkv_k(
    const unsigned short* __restrict__ xbf,
    const unsigned short* __restrict__ wbf,
    unsigned short* __restrict__ qkv)
{
    __shared__ unsigned short As[128][32];
    __shared__ unsigned short Bs[128][32];
    const int tid = threadIdx.x;
    const int l = tid & 63, w = tid >> 6;
    const int wr = w >> 1, wc = w & 1;
    const long row0 = (long)blockIdx.y * 128;
    const int col0 = blockIdx.x * 128;

    f32x4 acc[4][4] = {};
    const int fr = l & 15, hi = l >> 4;

    const int sr = tid >> 2;
    const int sc = (tid & 3) * 8;
    const unsigned short* ga = &xbf[(row0 + sr) * 1024 + sc];
    const unsigned short* gb = &wbf[(long)(col0 + sr) * 1024 + sc];
    unsigned short* la = &As[w * 16][0];
    unsigned short* lb = &Bs[w * 16][0];

    for (int k0 = 0; k0 < 1024; k0 += 32) {
        __syncthreads();
        gload_lds16(ga + k0, la);
        gload_lds16(ga + 64 * 1024 + k0, la + 64 * 32);
        gload_lds16(gb + k0, lb);
        gload_lds16(gb + 64 * 1024 + k0, lb + 64 * 32);
        __syncthreads();

        sh8 af[4], bf[4];
#pragma unroll
        for (int i = 0; i < 4; ++i) {
            af[i] = *(const sh8*)&As[wr * 64 + i * 16 + fr][hi * 8];
            bf[i] = *(const sh8*)&Bs[wc * 64 + i * 16 + fr][hi * 8];
        }
#pragma unroll
        for (int i = 0; i < 4; ++i)
#pragma unroll
            for (int j = 0; j < 4; ++j)
                acc[i][j] = MFMA16(af[i], bf[j], acc[i][j]);
    }

    const float scale = (col0 < 1024) ? 0.1803368801f : 1.0f;
    const int rg = hi * 4, cg = l & 15;
#pragma unroll
    for (int i = 0; i < 4; ++i)
#pragma unroll
        for (int j = 0; j < 4; ++j) {
            long gr = row0 + wr * 64 + i * 16 + rg;
            int gc = col0 + wc * 64 + j * 16 + cg;
#pragma unroll
            for (int r = 0; r < 4; ++r)
                qkv[(gr + r) * 3072 + gc] = f2bf(acc[i][j][r] * scale);
        }
}

// ---------------------------------------------------------------------------
// Flash attention over dense compacted Kc. R10: K staged via global_load_lds
// (linear dest, XOR swizzle pre-applied to per-lane SOURCE address — content
// convention Kl[r][c'] = global chunk c'^(r&7), identical to R9's, so the
// read side is byte-identical). V reg-staged from linear compacted rows
// (T14 prefetch kept); all per-tile idx/min/64-bit gather math removed.
// ---------------------------------------------------------------------------
__global__ __launch_bounds__(256) void attn_k(
    const unsigned short* __restrict__ qkv, const unsigned short* __restrict__ Kc,
    const int* __restrict__ cnt, unsigned short* __restrict__ ao, int b0)
{
    __shared__ unsigned short Kl[64][64];
    __shared__ unsigned short Vt[64][64];
    __shared__ float biasf[64];
    __shared__ unsigned short Pl[4][16][72];

    const int tid = threadIdx.x;
    const int l = tid & 63, w = tid >> 6;
    const int fr = l & 15, hi = l >> 4;

    // T1: bijective XCD swizzle
    int nwg = gridDim.x;
    int wgid = ((nwg & 7) == 0) ? ((blockIdx.x & 7) * (nwg >> 3) + (blockIdx.x >> 3))
                                : blockIdx.x;
    const int qb = wgid & 31;
    const int h  = (wgid >> 5) & 15;
    const int b  = wgid >> 9;
    const int q0 = qb * 64;
    const long base = (long)b * 2048;

    const int nc = cnt[b0 + b];
    const int nt = (nc + 63) >> 6;

    sh8 qf0, qf1;
    {
        const unsigned short* qp = &qkv[(base + q0 + w * 16 + fr) * 3072 + h * 64 + hi * 8];
        qf0 = *(const sh8*)qp;
        qf1 = *(const sh8*)(qp + 32);
    }

    f32x4 acc[4] = {};
    float mrow = -1e30f;
    float lrow = 0.f;

    const long TS = 262144;                       // 64 rows * 4096 B per tile
    const char* kc_b = (const char*)Kc + (size_t)b * 2048 * 4096;

    // K gload source: lane covers LDS slot (row8 = l>>3, chunk = l&7) of an
    // 8-row slab; source chunk = (l&7)^(l>>3) so LDS holds c'^(r&7).
    const int l8 = l >> 3, c8 = l & 7;
    const char* ksrc = kc_b + (size_t)(w * 16 + l8) * 4096 + h * 128 + ((c8 ^ l8) * 16);
    unsigned short* kdst0 = &Kl[w * 16][0];
    unsigned short* kdst1 = &Kl[w * 16 + 8][0];

    // V reg-staging source (linear compacted rows), T14-prefetched
    const int kv2 = tid >> 3, dc = tid & 7;
    const char* vp0 = kc_b + (size_t)(2 * kv2) * 4096 + 2048 + h * 128 + dc * 16;
    uint4 v0r = *(const uint4*)vp0;
    uint4 v1r = *(const uint4*)(vp0 + 4096);
    vp0 += TS;

    for (int t = 0; t < nt; ++t) {
        __syncthreads();                  // prior tile's LDS reads done
        // K tile t -> LDS (async, drained by next barrier)
        gload_lds16(ksrc, kdst0);
        gload_lds16(ksrc + 8 * 4096, kdst1);
        ksrc += TS;
        // V regs -> Vt (transposed, chunk-XOR swizzled) — same repack as R9
        {
            unsigned int w0[4] = { v0r.x, v0r.y, v0r.z, v0r.w };
            unsigned int w1[4] = { v1r.x, v1r.y, v1r.z, v1r.w };
            int cc2 = kv2 >> 2, pos = (2 * kv2) & 7;
#pragma unroll
            for (int jj = 0; jj < 4; ++jj) {
                int de = dc * 8 + 2 * jj;
                unsigned int pe = (w0[jj] & 0xffffu) | (w1[jj] << 16);
                unsigned int po = (w0[jj] >> 16) | (w1[jj] & 0xffff0000u);
                int fde = (2 * jj) ^ dc;
                int fdo = (2 * jj + 1) ^ dc;
                *(unsigned int*)&Vt[de][((cc2 ^ fde) * 8) + pos] = pe;
                *(unsigned int*)&Vt[de + 1][((cc2 ^ fdo) * 8) + pos] = po;
            }
        }
        if (tid < 64) biasf[tid] = (t * 64 + tid < nc) ? 0.0f : -1e9f;
        __syncthreads();                  // K resident, Vt written

        // T14: prefetch next tile's V into regs (lands under compute)
        if (t + 1 < nt) {
            v0r = *(const uint4*)vp0;
            v1r = *(const uint4*)(vp0 + 4096);
            vp0 += TS;
        }

        // K fragments (read side unchanged)
        sh8 kf[4][2];
#pragma unroll
        for (int tt = 0; tt < 4; ++tt) {
            const unsigned short* kp = &Kl[tt * 16 + fr][0];
#pragma unroll
            for (int c = 0; c < 2; ++c)
                kf[tt][c] = *(const sh8*)&kp[((4 * c + hi) ^ (fr & 7)) * 8];
        }

        // S^T = K Q
        f32x4 s[4] = {};
        __builtin_amdgcn_s_setprio(1);
#pragma unroll
        for (int tt = 0; tt < 4; ++tt) {
            s[tt] = MFMA16(kf[tt][0], qf0, s[tt]);
            s[tt] = MFMA16(kf[tt][1], qf1, s[tt]);
        }
        __builtin_amdgcn_s_setprio(0);
#pragma unroll
        for (int tt = 0; tt < 4; ++tt)
            s[tt] += *(const f32x4*)&biasf[tt * 16 + 4 * hi];

        float pm = s[0][0];
#pragma unroll
        for (int tt = 0; tt < 4; ++tt)
#pragma unroll
            for (int r = 0; r < 4; ++r) pm = fmaxf(pm, s[tt][r]);
        pm = redmax_hi(pm);

        if (!__all(pm <= mrow)) {           // defer-max: wave-uniform skip
            float mn = fmaxf(mrow, pm);
            float scl = __builtin_amdgcn_exp2f(mrow - mn);
            lrow *= scl;
#pragma unroll
            for (int df = 0; df < 4; ++df) acc[df] *= scl;
            mrow = mn;
        }

        float ps = 0.f;
#pragma unroll
        for (int tt = 0; tt < 4; ++tt)
#pragma unroll
            for (int r = 0; r < 4; ++r) {
                float p = __builtin_amdgcn_exp2f(s[tt][r] - mrow);
                s[tt][r] = p;
                ps += p;
            }
        lrow += redsum_hi(ps);

        // P -> per-wave LDS (4x b64)
#pragma unroll
        for (int tt = 0; tt < 4; ++tt) {
            uint2 pw = { pack2bf(s[tt][0], s[tt][1]), pack2bf(s[tt][2], s[tt][3]) };
            *(uint2*)&Pl[w][fr][tt * 16 + hi * 4] = pw;
        }

        // O^T += V^T * P
#pragma unroll
        for (int c = 0; c < 2; ++c) {
            sh8 pa = *(const sh8*)&Pl[w][fr][c * 32 + hi * 8];
            __builtin_amdgcn_s_setprio(1);
#pragma unroll
            for (int df = 0; df < 4; ++df) {
                int d = df * 16 + fr;
                int fd = (d & 7) ^ (d >> 3);
                sh8 vfr = *(const sh8*)&Vt[d][((4 * c + hi) ^ fd) * 8];
                acc[df] = MFMA16(vfr, pa, acc[df]);
            }
            __builtin_amdgcn_s_setprio(0);
        }
    }

    {
        float inv = 1.0f / lrow;
        long qr = base + q0 + w * 16 + fr;
        unsigned short* op = &ao[qr * 1024 + h * 64];
#pragma unroll
        for (int df = 0; df < 4; ++df) {
            f32x4 o = acc[df];
            uint2 ow = { pack2bf(o[0] * inv, o[1] * inv), pack2bf(o[2] * inv, o[3] * inv) };
            *(uint2*)&op[df * 16 + hi * 4] = ow;
        }
    }
}

// ---------------------------------------------------------------------------
// Output projection, m97-style staging (unchanged).
// ---------------------------------------------------------------------------
__global__ __launch_bounds__(256) void gemm_out_k(
    const unsigned short* __restrict__ ao, const unsigned short* __restrict__ wob,
    const float* __restrict__ bo, float* __restrict__ out)
{
    __shared__ unsigned short As[128][32];
    __shared__ unsigned short Bs[128][32];
    const int tid = threadIdx.x;
    const int l = tid & 63, w = tid >> 6;
    const int wr = w >> 1, wc = w & 1;
    const long row0 = (long)blockIdx.y * 128;
    const int col0 = blockIdx.x * 128;

    f32x4 acc[4][4] = {};
    const int fr = l & 15, hi = l >> 4;

    const int sr = tid >> 2;
    const int sc = (tid & 3) * 8;
    const unsigned short* ga = &ao[(row0 + sr) * 1024 + sc];
    const unsigned short* gb = &wob[(long)(col0 + sr) * 1024 + sc];
    unsigned short* la = &As[w * 16][0];
    unsigned short* lb = &Bs[w * 16][0];

    for (int k0 = 0; k0 < 1024; k0 += 32) {
        __syncthreads();
        gload_lds16(ga + k0, la);
        gload_lds16(ga + 64 * 1024 + k0, la + 64 * 32);
        gload_lds16(gb + k0, lb);
        gload_lds16(gb + 64 * 1024 + k0, lb + 64 * 32);
        __syncthreads();

        sh8 af[4], bf[4];
#pragma unroll
        for (int i = 0; i < 4; ++i) {
            af[i] = *(const sh8*)&As[wr * 64 + i * 16 + fr][hi * 8];
            bf[i] = *(const sh8*)&Bs[wc * 64 + i * 16 + fr][hi * 8];
        }
#pragma unroll
        for (int i = 0; i < 4; ++i)
#pragma unroll
            for (int j = 0; j < 4; ++j)
                acc[i][j] = MFMA16(af[i], bf[j], acc[i][j]);
    }

    const int rg = hi * 4, cg = l & 15;
#pragma unroll
    for (int i = 0; i < 4; ++i)
#pragma unroll
        for (int j = 0; j < 4; ++j) {
            long gr = row0 + wr * 64 + i * 16 + rg;
            int gc = col0 + wc * 64 + j * 16 + cg;
            float bb = bo[gc];
#pragma unroll
            for (int r = 0; r < 4; ++r)
                out[(gr + r) * 1024 + gc] = acc[i][j][r] + bb;
        }
}

extern "C" void kernel_launch(void* const* d_in, const int* in_sizes, int n_in,
                              void* d_out, int out_size, void* d_ws, size_t ws_size,
                              hipStream_t stream) {
    const float* x    = (const float*)d_in[0];
    const int*   mask = (const int*)d_in[1];
    const float* Wq   = (const float*)d_in[2];
    const float* Wk   = (const float*)d_in[3];
    const float* Wv   = (const float*)d_in[4];
    const float* Wo   = (const float*)d_in[5];
    const float* bo   = (const float*)d_in[6];
    float* out = (float*)d_out;

    const size_t wbf_bytes = (size_t)4096 * 1024 * 2;              // 8 MiB
    const size_t idx_bytes = (size_t)4 * 2048 * 4 + 64;
    const size_t xbf_per_b = (size_t)2048 * 1024 * 2;              // 4 MiB
    const size_t qkv_per_b = (size_t)2048 * 3072 * 2;              // 12 MiB
    const size_t ao_per_b  = (size_t)2048 * 1024 * 2;              // 4 MiB
    const size_t kc_per_b  = (size_t)2048 * 2048 * 2;              // 8 MiB
    const size_t per_b = xbf_per_b + qkv_per_b + ao_per_b + kc_per_b; // 28 MiB

    size_t fixed = wbf_bytes + idx_bytes;
    size_t avail = (ws_size > fixed) ? (ws_size - fixed) : 0;
    int bchunk = (avail >= per_b) ? (int)(avail / per_b) : 1;
    if (bchunk > 4) bchunk = 4;

    char* p = (char*)d_ws;
    unsigned short* wbf = (unsigned short*)p;            p += wbf_bytes;
    int* idxp = (int*)p;                                 p += (size_t)4 * 2048 * 4;
    int* cntp = (int*)p;                                 p += 64;
    unsigned short* xbf = (unsigned short*)p;            p += (size_t)bchunk * xbf_per_b;
    unsigned short* qkv = (unsigned short*)p;            p += (size_t)bchunk * qkv_per_b;
    unsigned short* ao  = (unsigned short*)p;            p += (size_t)bchunk * ao_per_b;
    unsigned short* Kc  = (unsigned short*)p;

    cvt_w_k<<<4096, 256, 0, stream>>>(Wq, Wk, Wv, Wo, wbf);
    compact_k<<<4, 64, 0, stream>>>(mask, idxp, cntp);

    for (int b0 = 0; b0 < 4; b0 += bchunk) {
        int bc = (4 - b0 < bchunk) ? (4 - b0) : bchunk;
        cvt_x_k<<<2048, 256, 0, stream>>>(
            x + (size_t)b0 * 2048 * 1024, xbf, bc * 524288);
        gemm_qkv_k<<<dim3(24, bc * 16), 256, 0, stream>>>(xbf, wbf, qkv);
        kvgather_k<<<dim3(8, 32, bc), 256, 0, stream>>>(qkv, idxp, cntp, Kc, b0);
        attn_k<<<dim3(512 * bc), 256, 0, stream>>>(qkv, Kc, cntp, ao, b0);
        gemm_out_k<<<dim3(8, bc * 16), 256, 0, stream>>>(
            ao, wbf + (size_t)3072 * 1024, bo, out + (size_t)b0 * 2048 * 1024);
    }
}